// Round 4
// baseline (178.346 us; speedup 1.0000x reference)
//
#include <hip/hip_runtime.h>

// RelationalGraphConvLayer: out[b,m,u] = relu(sum_e (adj[b,e]@feat[b]) @ ker[b,e])
// B=256, E=5, N=128, ATOM=64, UNITS=128, fp32 in/out, bf16 MFMA compute.
//
// v4: break the 1-block/CU phase-lock. Grid 512 (each block = one half of one
// sample's 128 output rows), 512 threads / 8 waves, LDS 64 KB -> 2 blocks/CU.
// Two independent barrier domains per CU fill each other's latency shadows.
// XCD-swizzle co-locates both halves of a sample on one XCD so the duplicated
// ker/feat fetches are L2 hits. Per-wave structure unchanged from v3
// (frag-order LDS, reg prefetch of e+1, LDS-only barrier).

typedef __attribute__((ext_vector_type(8))) short s8v;  // 8 x bf16 (4 VGPRs) MFMA A/B frag
typedef __attribute__((ext_vector_type(4))) float f4v;  // MFMA C/D frag / float4 load

__device__ __forceinline__ short f2bf(float f) {
    // fp32 -> bf16 round-to-nearest-even (inputs finite; no NaN handling needed)
    unsigned u = __builtin_bit_cast(unsigned, f);
    u += 0x7FFFu + ((u >> 16) & 1u);
    return (short)(u >> 16);
}

// LDS-only barrier: drain this wave's LDS ops, then rendezvous. Global (vmcnt)
// loads stay outstanding across it. sched_barrier fences LDS-read hoisting.
__device__ __forceinline__ void lds_barrier() {
    asm volatile("s_waitcnt lgkmcnt(0)" ::: "memory");
    __builtin_amdgcn_s_barrier();
    __builtin_amdgcn_sched_barrier(0);
}

__global__ __launch_bounds__(512, 4)
void rgc_kernel(const float* __restrict__ adj,
                const float* __restrict__ feat,
                const float* __restrict__ ker,
                float* __restrict__ out)
{
    // Frag-order layouts: [tile][lane*8 shorts]. A wave's ds_read_b128 of one
    // tile is base + lane*16B -> linear 1KB, zero bank conflicts.
    __shared__ __align__(16) short featB[16 * 512];    // tile (d16*4+k16): feat[32k16+8q+j][16d16+c16] ; 16 KB
    __shared__ __align__(16) short kerB[2][16 * 512];  // tile (u16*2+k):   ker[32k+8q+j][16u16+c16]   ; 32 KB
    __shared__ __align__(16) short YA[8][2 * 512];     // per-wave, tile k: Y[row16+c16][32k+8q+j]     ; 16 KB

    const int tid  = threadIdx.x;
    const int w    = tid >> 6;    // wave 0..7
    const int lane = tid & 63;
    const int c16  = lane & 15;
    const int quad = lane >> 4;
    const int g    = w >> 1;      // row group within half: rows [16g, 16g+16)
    const int h    = w & 1;       // u-half: u16 tiles [4h, 4h+4)

    // XCD swizzle (512 % 8 == 0 -> bijective): both halves of a sample land on
    // the same XCD so their shared ker/feat fetches hit that XCD's L2.
    const int bid  = blockIdx.x;
    const int wg   = ((bid & 7) << 6) | (bid >> 3);
    const int b    = wg >> 1;
    const int half = wg & 1;
    const int rowBase = 64 * half + 16 * g;  // this wave's 16 output rows

    const float* adjB = adj  + (size_t)b * (5 * 128 * 128);
    const float* feG  = feat + (size_t)b * (128 * 64);
    const float* keG  = ker  + (size_t)b * (5 * 64 * 128);
    float*       outB = out  + (size_t)b * (128 * 128);

    // ---- adjacency e=0 into regs (consumed at loop top, reloaded for e+1) ----
    f4v a0[4], a1[4];
    {
        const float* ap = adjB + (rowBase + c16) * 128 + 8 * quad;
        #pragma unroll
        for (int k16 = 0; k16 < 4; ++k16) {
            a0[k16] = *(const f4v*)(ap + 32 * k16);
            a1[k16] = *(const f4v*)(ap + 32 * k16 + 4);
        }
    }

    // ---- stage featB once: column loads (lane = d -> coalesced), b128 writes ----
    {
        const int fd = tid & 63;  // d
        #pragma unroll
        for (int i = 0; i < 2; ++i) {
            const int fn0 = i * 64 + (tid >> 6) * 8;  // 8 consecutive n per pass
            float fv[8];
            #pragma unroll
            for (int j = 0; j < 8; ++j)
                fv[j] = feG[(fn0 + j) * 64 + fd];
            s8v v;
            #pragma unroll
            for (int j = 0; j < 8; ++j) v[j] = f2bf(fv[j]);
            *(s8v*)&featB[((fd >> 4) * 4 + (fn0 >> 5)) * 512 + ((fn0 >> 3) & 3) * 128 + (fd & 15) * 8] = v;
        }
    }

    // ---- stage kerB[0]: column loads (lane = u -> coalesced), b128 writes ----
    const int ku   = tid & 127;              // u
    const int kd0a = (tid >> 7) * 8;         // first d-octet
    const int kd0b = 32 + kd0a;              // second d-octet
    const int kOffA = (ku >> 4) * 1024 + (kd0a >> 5) * 512 + ((kd0a >> 3) & 3) * 128 + (ku & 15) * 8;
    const int kOffB = (ku >> 4) * 1024 + (kd0b >> 5) * 512 + ((kd0b >> 3) & 3) * 128 + (ku & 15) * 8;
    {
        float kv[16];
        #pragma unroll
        for (int j = 0; j < 8; ++j) kv[j]     = keG[(kd0a + j) * 128 + ku];
        #pragma unroll
        for (int j = 0; j < 8; ++j) kv[8 + j] = keG[(kd0b + j) * 128 + ku];
        s8v va, vb;
        #pragma unroll
        for (int j = 0; j < 8; ++j) { va[j] = f2bf(kv[j]); vb[j] = f2bf(kv[8 + j]); }
        *(s8v*)&kerB[0][kOffA] = va;
        *(s8v*)&kerB[0][kOffB] = vb;
    }
    lds_barrier();

    f4v oacc[4] = {};  // out tiles (m16 = rowBase, u16 = 4h..4h+3)

    for (int e = 0; e < 5; ++e) {
        // ---- convert this e's adj regs to A-frags (frees a0/a1 for prefetch) ----
        s8v af[4];
        #pragma unroll
        for (int k16 = 0; k16 < 4; ++k16) {
            #pragma unroll
            for (int j = 0; j < 4; ++j) {
                af[k16][j]     = f2bf(a0[k16][j]);
                af[k16][4 + j] = f2bf(a1[k16][j]);
            }
        }

        // ---- prefetch e+1: ker columns then adj rows; pinned above matmuls ----
        float kv[16];
        if (e < 4) {
            const float* kp = keG + (e + 1) * (64 * 128);
            #pragma unroll
            for (int j = 0; j < 8; ++j) kv[j]     = kp[(kd0a + j) * 128 + ku];
            #pragma unroll
            for (int j = 0; j < 8; ++j) kv[8 + j] = kp[(kd0b + j) * 128 + ku];
            const float* ap = adjB + (e + 1) * (128 * 128) + (rowBase + c16) * 128 + 8 * quad;
            #pragma unroll
            for (int k16 = 0; k16 < 4; ++k16) {
                a0[k16] = *(const f4v*)(ap + 32 * k16);
                a1[k16] = *(const f4v*)(ap + 32 * k16 + 4);
            }
            __builtin_amdgcn_sched_barrier(0);  // loads may not sink below this point
        }

        // ---- matmul1: Y[rowBase..rowBase+16) = adj_e @ feat (dup per wave pair) ----
        f4v yacc[4] = {};
        #pragma unroll
        for (int k16 = 0; k16 < 4; ++k16)
            #pragma unroll
            for (int d16 = 0; d16 < 4; ++d16) {
                s8v bf = *(const s8v*)&featB[(d16 * 4 + k16) * 512 + lane * 8];
                yacc[d16] = __builtin_amdgcn_mfma_f32_16x16x32_bf16(af[k16], bf, yacc[d16], 0, 0, 0);
            }

        // ---- Y -> wave-private LDS, stored directly in A-frag order ----
        // value yacc[d16][r] is Y[rowBase+4q+r][16d16+c16] -> tile k=d16>>1,
        // quad_t=(2d16+(c16>>3))&3, lane_c16=4q+r, j=c16&7.
        #pragma unroll
        for (int d16 = 0; d16 < 4; ++d16) {
            const int base = (d16 >> 1) * 512 + ((2 * d16 + (c16 >> 3)) & 3) * 128 + (c16 & 7);
            #pragma unroll
            for (int r = 0; r < 4; ++r)
                YA[w][base + (4 * quad + r) * 8] = f2bf(yacc[d16][r]);
        }

        // ---- matmul2: out[rows rowBase..][u-half h] += Y @ ker_e ----
        {
            const int buf = e & 1;
            s8v afr0 = *(const s8v*)&YA[w][lane * 8];
            s8v afr1 = *(const s8v*)&YA[w][512 + lane * 8];
            #pragma unroll
            for (int n = 0; n < 4; ++n) {
                const int u16 = 4 * h + n;
                s8v b0 = *(const s8v*)&kerB[buf][(u16 * 2 + 0) * 512 + lane * 8];
                s8v b1 = *(const s8v*)&kerB[buf][(u16 * 2 + 1) * 512 + lane * 8];
                oacc[n] = __builtin_amdgcn_mfma_f32_16x16x32_bf16(afr0, b0, oacc[n], 0, 0, 0);
                oacc[n] = __builtin_amdgcn_mfma_f32_16x16x32_bf16(afr1, b1, oacc[n], 0, 0, 0);
            }
        }

        // ---- stage next kerB into the other buffer; LDS-only barrier protects
        //      the rotation (prefetched adj loads stay in flight) ----
        if (e < 4) {
            s8v va, vb;
            #pragma unroll
            for (int j = 0; j < 8; ++j) { va[j] = f2bf(kv[j]); vb[j] = f2bf(kv[8 + j]); }
            *(s8v*)&kerB[(e + 1) & 1][kOffA] = va;
            *(s8v*)&kerB[(e + 1) & 1][kOffB] = vb;
            lds_barrier();
        }
    }

    // ---- epilogue: relu + store ----
    #pragma unroll
    for (int n = 0; n < 4; ++n)
        #pragma unroll
        for (int r = 0; r < 4; ++r)
            outB[(rowBase + 4 * quad + r) * 128 + 16 * (4 * h + n) + c16] = fmaxf(oacc[n][r], 0.f);
}

extern "C" void kernel_launch(void* const* d_in, const int* in_sizes, int n_in,
                              void* d_out, int out_size, void* d_ws, size_t ws_size,
                              hipStream_t stream)
{
    const float* adj  = (const float*)d_in[0];
    const float* feat = (const float*)d_in[1];
    const float* ker  = (const float*)d_in[2];
    rgc_kernel<<<512, 512, 0, stream>>>(adj, feat, ker, (float*)d_out);
}

// Round 5
// 170.998 us; speedup vs baseline: 1.0430x; 1.0430x over previous
//
#include <hip/hip_runtime.h>

// RelationalGraphConvLayer: out[b,m,u] = relu(sum_e (adj[b,e]@feat[b]) @ ker[b,e])
// B=256, E=5, N=128, ATOM=64, UNITS=128, fp32 in/out, bf16 MFMA compute.
//
// v5: barrier-free e-loop. All five ker tiles are staged to LDS in the prologue
// (featB 16K + kerB[5] 80K + YA 32K = 128K <= 160K), so the e-loop has NO
// barriers and NO loop-carried staging: waves free-run and de-phase, overlapping
// each other's memory stalls (v2-v4 showed the per-e barrier phase-locked all 16
// waves around a cold-HBM ker load each iteration). Grid 256 x 1024 (block =
// one sample; no duplicated staging, unlike v4).

typedef __attribute__((ext_vector_type(8))) short s8v;  // 8 x bf16 (4 VGPRs) MFMA A/B frag
typedef __attribute__((ext_vector_type(4))) float f4v;  // MFMA C/D frag / float4 load

__device__ __forceinline__ short f2bf(float f) {
    // fp32 -> bf16 round-to-nearest-even (inputs finite; no NaN handling needed)
    unsigned u = __builtin_bit_cast(unsigned, f);
    u += 0x7FFFu + ((u >> 16) & 1u);
    return (short)(u >> 16);
}

// LDS-only barrier: drain this wave's LDS ops, then rendezvous. Global (vmcnt)
// loads stay outstanding across it. sched_barrier fences LDS-read hoisting.
__device__ __forceinline__ void lds_barrier() {
    asm volatile("s_waitcnt lgkmcnt(0)" ::: "memory");
    __builtin_amdgcn_s_barrier();
    __builtin_amdgcn_sched_barrier(0);
}

__global__ __launch_bounds__(1024, 4)
void rgc_kernel(const float* __restrict__ adj,
                const float* __restrict__ feat,
                const float* __restrict__ ker,
                float* __restrict__ out)
{
    // Frag-order layouts: [tile][lane*8 shorts]. A wave's ds_read_b128 of one
    // tile is base + lane*16B -> linear 1KB, zero bank conflicts.
    __shared__ __align__(16) short featB[16 * 512];    // tile (d16*4+k16): feat[32k16+8q+j][16d16+c16] ; 16 KB
    __shared__ __align__(16) short kerB[5][16 * 512];  // [e], tile (u16*2+k): ker[32k+8q+j][16u16+c16] ; 80 KB
    __shared__ __align__(16) short YA[16][2 * 512];    // per-wave, tile k: Y[16g+c16][32k+8q+j]        ; 32 KB

    const int tid  = threadIdx.x;
    const int w    = tid >> 6;    // wave 0..15
    const int lane = tid & 63;
    const int c16  = lane & 15;
    const int quad = lane >> 4;
    const int g    = w >> 1;      // row group: rows [16g, 16g+16)
    const int h    = w & 1;       // u-half: u16 tiles [4h, 4h+4)

    const int b = blockIdx.x;
    const float* adjB = adj  + (size_t)b * (5 * 128 * 128);
    const float* feG  = feat + (size_t)b * (128 * 64);
    const float* keG  = ker  + (size_t)b * (5 * 64 * 128);
    float*       outB = out  + (size_t)b * (128 * 128);

    // ---- adjacency e=0 into regs (issued first; consumed after the barrier) ----
    f4v a0[4], a1[4];
    {
        const float* ap = adjB + (16 * g + c16) * 128 + 8 * quad;
        #pragma unroll
        for (int k16 = 0; k16 < 4; ++k16) {
            a0[k16] = *(const f4v*)(ap + 32 * k16);
            a1[k16] = *(const f4v*)(ap + 32 * k16 + 4);
        }
    }

    // ---- prologue staging: feat + ALL FIVE ker tiles; issue every global load
    //      first (max MLP), then convert+store. One barrier total. ----
    const int fd  = tid & 63;         // feat: d   (lane-contiguous -> coalesced)
    const int fn0 = (tid >> 6) * 8;   // feat: 8 consecutive n per thread
    const int ku  = tid & 127;        // ker: u    (lane-contiguous -> coalesced)
    const int kd0 = (tid >> 7) * 8;   // ker: 8 consecutive d per thread
    const int kerB_off = (ku >> 4) * 1024 + (kd0 >> 5) * 512 + ((kd0 >> 3) & 3) * 128 + (ku & 15) * 8;

    float fv[8];
    #pragma unroll
    for (int j = 0; j < 8; ++j)
        fv[j] = feG[(fn0 + j) * 64 + fd];

    float kv[5][8];
    #pragma unroll
    for (int e = 0; e < 5; ++e)
        #pragma unroll
        for (int j = 0; j < 8; ++j)
            kv[e][j] = keG[e * (64 * 128) + (kd0 + j) * 128 + ku];

    {
        s8v v;
        #pragma unroll
        for (int j = 0; j < 8; ++j) v[j] = f2bf(fv[j]);
        *(s8v*)&featB[((fd >> 4) * 4 + (fn0 >> 5)) * 512 + ((fn0 >> 3) & 3) * 128 + (fd & 15) * 8] = v;
    }
    #pragma unroll
    for (int e = 0; e < 5; ++e) {
        s8v v;
        #pragma unroll
        for (int j = 0; j < 8; ++j) v[j] = f2bf(kv[e][j]);
        *(s8v*)&kerB[e][kerB_off] = v;
    }
    lds_barrier();  // the ONLY barrier; adj e=0 loads stay in flight across it

    f4v oacc[4] = {};  // out tiles (m16 = g, u16 = 4h..4h+3)

    for (int e = 0; e < 5; ++e) {
        // ---- convert this e's adj regs to A-frags (frees a0/a1 for prefetch) ----
        s8v af[4];
        #pragma unroll
        for (int k16 = 0; k16 < 4; ++k16) {
            #pragma unroll
            for (int j = 0; j < 4; ++j) {
                af[k16][j]     = f2bf(a0[k16][j]);
                af[k16][4 + j] = f2bf(a1[k16][j]);
            }
        }

        // ---- prefetch e+1 adj rows; pinned so the latency is covered by the
        //      matmuls below (and by other free-running waves) ----
        if (e < 4) {
            const float* ap = adjB + (e + 1) * (128 * 128) + (16 * g + c16) * 128 + 8 * quad;
            #pragma unroll
            for (int k16 = 0; k16 < 4; ++k16) {
                a0[k16] = *(const f4v*)(ap + 32 * k16);
                a1[k16] = *(const f4v*)(ap + 32 * k16 + 4);
            }
            __builtin_amdgcn_sched_barrier(0);  // loads may not sink below this point
        }

        // ---- matmul1: Y[16g..16g+16) = adj_e @ feat (duplicated per wave pair) ----
        f4v yacc[4] = {};
        #pragma unroll
        for (int k16 = 0; k16 < 4; ++k16)
            #pragma unroll
            for (int d16 = 0; d16 < 4; ++d16) {
                s8v bf = *(const s8v*)&featB[(d16 * 4 + k16) * 512 + lane * 8];
                yacc[d16] = __builtin_amdgcn_mfma_f32_16x16x32_bf16(af[k16], bf, yacc[d16], 0, 0, 0);
            }

        // ---- Y -> wave-private LDS, stored directly in A-frag order ----
        // value yacc[d16][r] is Y[16g+4q+r][16d16+c16] -> tile k=d16>>1,
        // quad_t=(2d16+(c16>>3))&3, lane_c16=4q+r, j=c16&7.
        #pragma unroll
        for (int d16 = 0; d16 < 4; ++d16) {
            const int base = (d16 >> 1) * 512 + ((2 * d16 + (c16 >> 3)) & 3) * 128 + (c16 & 7);
            #pragma unroll
            for (int r = 0; r < 4; ++r)
                YA[w][base + (4 * quad + r) * 8] = f2bf(yacc[d16][r]);
        }

        // ---- matmul2: out[rows g][u-half h] += Y @ ker_e (no barrier needed:
        //      kerB[e] is read-only after the prologue, YA is wave-private) ----
        {
            s8v afr0 = *(const s8v*)&YA[w][lane * 8];
            s8v afr1 = *(const s8v*)&YA[w][512 + lane * 8];
            #pragma unroll
            for (int n = 0; n < 4; ++n) {
                const int u16 = 4 * h + n;
                s8v b0 = *(const s8v*)&kerB[e][(u16 * 2 + 0) * 512 + lane * 8];
                s8v b1 = *(const s8v*)&kerB[e][(u16 * 2 + 1) * 512 + lane * 8];
                oacc[n] = __builtin_amdgcn_mfma_f32_16x16x32_bf16(afr0, b0, oacc[n], 0, 0, 0);
                oacc[n] = __builtin_amdgcn_mfma_f32_16x16x32_bf16(afr1, b1, oacc[n], 0, 0, 0);
            }
        }
    }

    // ---- epilogue: relu + store ----
    #pragma unroll
    for (int n = 0; n < 4; ++n)
        #pragma unroll
        for (int r = 0; r < 4; ++r)
            outB[(16 * g + 4 * quad + r) * 128 + 16 * (4 * h + n) + c16] = fmaxf(oacc[n][r], 0.f);
}

extern "C" void kernel_launch(void* const* d_in, const int* in_sizes, int n_in,
                              void* d_out, int out_size, void* d_ws, size_t ws_size,
                              hipStream_t stream)
{
    const float* adj  = (const float*)d_in[0];
    const float* feat = (const float*)d_in[1];
    const float* ker  = (const float*)d_in[2];
    rgc_kernel<<<256, 1024, 0, stream>>>(adj, feat, ker, (float*)d_out);
}

// Round 6
// 170.203 us; speedup vs baseline: 1.0478x; 1.0047x over previous
//
#include <hip/hip_runtime.h>

// RelationalGraphConvLayer: out[b,m,u] = relu(sum_e (adj[b,e]@feat[b]) @ ker[b,e])
// B=256, E=5, N=128, ATOM=64, UNITS=128, fp32 in/out, bf16 MFMA compute.
//
// v6: W-first reassociation. out = sum_e adj[e] @ W[e], W[e] = feat @ ker[e].
// W[e+1] is computed from LDS-resident feat/ker (no global dependency) and acts
// as the latency shadow for the adjacency stream -- the only global loads in the
// loop. adj vmcnt waits become counted (adj[e] converted while adj[e+1] is in
// flight). No matmul duplication; WB writes are packed ds_write_b64 (<=2-way).
// LDS: featA 16K + kerB[5] 80K + WB[2] 64K = 160 KB.

typedef __attribute__((ext_vector_type(8))) short s8v;  // 8 x bf16 MFMA A/B frag
typedef __attribute__((ext_vector_type(4))) short s4v;  // 4 x bf16 packed write
typedef __attribute__((ext_vector_type(4))) float f4v;  // MFMA C/D frag / float4

__device__ __forceinline__ short f2bf(float f) {
    // fp32 -> bf16 round-to-nearest-even (inputs finite; no NaN handling needed)
    unsigned u = __builtin_bit_cast(unsigned, f);
    u += 0x7FFFu + ((u >> 16) & 1u);
    return (short)(u >> 16);
}

// LDS-only barrier: drain this wave's LDS ops, then rendezvous. Global (vmcnt)
// loads stay outstanding across it. sched_barrier fences LDS-read hoisting.
__device__ __forceinline__ void lds_barrier() {
    asm volatile("s_waitcnt lgkmcnt(0)" ::: "memory");
    __builtin_amdgcn_s_barrier();
    __builtin_amdgcn_sched_barrier(0);
}

__global__ __launch_bounds__(1024, 4)
void rgc_kernel(const float* __restrict__ adj,
                const float* __restrict__ feat,
                const float* __restrict__ ker,
                float* __restrict__ out)
{
    // featA tile (n16*2+kk), lane l: feat[16*n16 + (l&15)][32*kk + 8*(l>>4) + j]   (A-frag order)
    // kerB[e] tile (u16*2+kk), lane l: ker[e][32*kk + 8*(l>>4) + j][16*u16 + (l&15)] (B-frag order)
    // WB[buf] tile (u16*4+k16), lane l: W[32*k16 + 8*(l>>4) + j][16*u16 + (l&15)]    (B-frag order)
    __shared__ __align__(16) short featA[16 * 512];    // 16 KB
    __shared__ __align__(16) short kerB[5][16 * 512];  // 80 KB
    __shared__ __align__(16) short WB[2][32 * 512];    // 64 KB

    const int tid  = threadIdx.x;
    const int w    = tid >> 6;    // wave 0..15
    const int lane = tid & 63;
    const int c16  = lane & 15;
    const int quad = lane >> 4;
    const int g    = w >> 1;      // out rows [16g,16g+16) ; also W n16 = g
    const int h    = w & 1;       // u16 strip [4h, 4h+4)

    const int b = blockIdx.x;
    const float* adjB = adj  + (size_t)b * (5 * 128 * 128);
    const float* feG  = feat + (size_t)b * (128 * 64);
    const float* keG  = ker  + (size_t)b * (5 * 64 * 128);
    float*       outB = out  + (size_t)b * (128 * 128);

    // ---- issue adj[0] loads first (converted at loop top; whole prologue is shadow) ----
    f4v a0[4], a1[4];
    {
        const float* ap = adjB + (16 * g + c16) * 128 + 8 * quad;
        #pragma unroll
        for (int k16 = 0; k16 < 4; ++k16) {
            a0[k16] = *(const f4v*)(ap + 32 * k16);
            a1[k16] = *(const f4v*)(ap + 32 * k16 + 4);
        }
    }

    // ---- stage featA: wave w stages tile w (n16 = w>>1, kk = w&1) ----
    {
        const float* fp = feG + (16 * (w >> 1) + c16) * 64 + 32 * (w & 1) + 8 * quad;
        f4v f0 = *(const f4v*)(fp);
        f4v f1 = *(const f4v*)(fp + 4);
        s8v v;
        #pragma unroll
        for (int j = 0; j < 4; ++j) { v[j] = f2bf(f0[j]); v[4 + j] = f2bf(f1[j]); }
        *(s8v*)&featA[w * 512 + lane * 8] = v;
    }

    // ---- stage kerB[0..4]: column loads (lane = u -> coalesced), b128 writes ----
    const int ku  = tid & 127;        // u
    const int kd0 = (tid >> 7) * 8;   // 8 consecutive d per thread
    const int kerB_off = (ku >> 4) * 1024 + (kd0 >> 5) * 512 + ((kd0 >> 3) & 3) * 128 + (ku & 15) * 8;
    {
        float kv[5][8];
        #pragma unroll
        for (int e = 0; e < 5; ++e)
            #pragma unroll
            for (int j = 0; j < 8; ++j)
                kv[e][j] = keG[e * (64 * 128) + (kd0 + j) * 128 + ku];
        #pragma unroll
        for (int e = 0; e < 5; ++e) {
            s8v v;
            #pragma unroll
            for (int j = 0; j < 8; ++j) v[j] = f2bf(kv[e][j]);
            *(s8v*)&kerB[e][kerB_off] = v;
        }
    }
    lds_barrier();

    // W-compute constants: wave computes W tiles (n16 = g, u16 = 4h+t).
    // wacc[r] = W[16g + 4*quad + r][16*u16 + c16] -> B-frag slot:
    //   k16 = g>>1 (uniform), q_t = 2*(g&1) + (quad>>1), j = 4*(quad&1) + r.
    const int wk16 = g >> 1;
    const int wqt  = 2 * (g & 1) + (quad >> 1);
    const int wj0  = 4 * (quad & 1);
    const int wbase = (wqt * 16 + c16) * 8 + wj0;

    // ---- W[0] into WB[0] ----
    {
        s8v fa0 = *(const s8v*)&featA[(g * 2 + 0) * 512 + lane * 8];
        s8v fa1 = *(const s8v*)&featA[(g * 2 + 1) * 512 + lane * 8];
        #pragma unroll
        for (int t = 0; t < 4; ++t) {
            const int u16 = 4 * h + t;
            s8v kb0 = *(const s8v*)&kerB[0][(u16 * 2 + 0) * 512 + lane * 8];
            s8v kb1 = *(const s8v*)&kerB[0][(u16 * 2 + 1) * 512 + lane * 8];
            f4v wacc = {};
            wacc = __builtin_amdgcn_mfma_f32_16x16x32_bf16(fa0, kb0, wacc, 0, 0, 0);
            wacc = __builtin_amdgcn_mfma_f32_16x16x32_bf16(fa1, kb1, wacc, 0, 0, 0);
            s4v pv;
            #pragma unroll
            for (int r = 0; r < 4; ++r) pv[r] = f2bf(wacc[r]);
            *(s4v*)&WB[0][(u16 * 4 + wk16) * 512 + wbase] = pv;
        }
    }
    lds_barrier();

    f4v oacc[4] = {};  // out tiles (m16 = g, u16 = 4h..4h+3)

    for (int e = 0; e < 5; ++e) {
        // ---- 1. convert adj[e] regs to A-frags (counted vmcnt wait: adj[e]
        //      was issued one full iteration ago) ----
        s8v af[4];
        #pragma unroll
        for (int k16 = 0; k16 < 4; ++k16) {
            #pragma unroll
            for (int j = 0; j < 4; ++j) {
                af[k16][j]     = f2bf(a0[k16][j]);
                af[k16][4 + j] = f2bf(a1[k16][j]);
            }
        }

        // ---- 2. issue adj[e+1]; pinned above the W-compute shadow ----
        if (e < 4) {
            const float* ap = adjB + (e + 1) * (128 * 128) + (16 * g + c16) * 128 + 8 * quad;
            #pragma unroll
            for (int k16 = 0; k16 < 4; ++k16) {
                a0[k16] = *(const f4v*)(ap + 32 * k16);
                a1[k16] = *(const f4v*)(ap + 32 * k16 + 4);
            }
            __builtin_amdgcn_sched_barrier(0);  // loads may not sink below this point

            // ---- 3+4. W[e+1] = feat @ ker[e+1] -> WB[(e+1)&1] (pure LDS+MFMA:
            //      the latency shadow for the adj[e+1] stream) ----
            s8v fa0 = *(const s8v*)&featA[(g * 2 + 0) * 512 + lane * 8];
            s8v fa1 = *(const s8v*)&featA[(g * 2 + 1) * 512 + lane * 8];
            #pragma unroll
            for (int t = 0; t < 4; ++t) {
                const int u16 = 4 * h + t;
                s8v kb0 = *(const s8v*)&kerB[e + 1][(u16 * 2 + 0) * 512 + lane * 8];
                s8v kb1 = *(const s8v*)&kerB[e + 1][(u16 * 2 + 1) * 512 + lane * 8];
                f4v wacc = {};
                wacc = __builtin_amdgcn_mfma_f32_16x16x32_bf16(fa0, kb0, wacc, 0, 0, 0);
                wacc = __builtin_amdgcn_mfma_f32_16x16x32_bf16(fa1, kb1, wacc, 0, 0, 0);
                s4v pv;
                #pragma unroll
                for (int r = 0; r < 4; ++r) pv[r] = f2bf(wacc[r]);
                *(s4v*)&WB[(e + 1) & 1][(u16 * 4 + wk16) * 512 + wbase] = pv;
            }
        }

        // ---- 5. out += adj[e] @ W[e]  (M=16, N=64, K=128; WB[e&1] ready since
        //      the previous barrier) ----
        #pragma unroll
        for (int n = 0; n < 4; ++n) {
            const int u16 = 4 * h + n;
            #pragma unroll
            for (int k16 = 0; k16 < 4; ++k16) {
                s8v bfr = *(const s8v*)&WB[e & 1][(u16 * 4 + k16) * 512 + lane * 8];
                oacc[n] = __builtin_amdgcn_mfma_f32_16x16x32_bf16(af[k16], bfr, oacc[n], 0, 0, 0);
            }
        }

        // ---- 6. barrier: WB[(e+1)&1] fully written before next iter reads it;
        //      also fences next iter's writes vs this iter's reads ----
        if (e < 4) lds_barrier();
    }

    // ---- epilogue: relu + store ----
    #pragma unroll
    for (int n = 0; n < 4; ++n)
        #pragma unroll
        for (int r = 0; r < 4; ++r)
            outB[(16 * g + 4 * quad + r) * 128 + 16 * (4 * h + n) + c16] = fmaxf(oacc[n][r], 0.f);
}

extern "C" void kernel_launch(void* const* d_in, const int* in_sizes, int n_in,
                              void* d_out, int out_size, void* d_ws, size_t ws_size,
                              hipStream_t stream)
{
    const float* adj  = (const float*)d_in[0];
    const float* feat = (const float*)d_in[1];
    const float* ker  = (const float*)d_in[2];
    rgc_kernel<<<256, 1024, 0, stream>>>(adj, feat, ker, (float*)d_out);
}